// Round 4
// baseline (281.884 us; speedup 1.0000x reference)
//
#include <hip/hip_runtime.h>

#define B 64
#define P 16320
#define NOBJ 32
#define NC 21

__device__ constexpr float LN99 = 4.59511985013459f;  // softmax(c1)>0.01 <=> c0-c1 < ln99

// ---------------- init: zero per-batch accumulators --------------------------
__global__ void k_init(int* num_pos, float* ll_b, float* lc_b) {
    int t = threadIdx.x;
    if (t < B) { num_pos[t] = 0; ll_b[t] = 0.f; lc_b[t] = 0.f; }
}

// ---------------- p1b: per-truth argmax over all P priors --------------------
// One block per (b, j-group of 8). Each thread accumulates 8 u64 running maxes
// (monotone_iou_bits<<32 | ~p) over its strided priors; shallow LDS tree.
// Init = pack(-1.0, prior 0) so an all-masked truth resolves to prior 0 (ref).
__global__ __launch_bounds__(1024) void k_p1b(
    const float* __restrict__ arm_loc, const float* __restrict__ arm_conf,
    const float* __restrict__ priors, const float* __restrict__ truths,
    unsigned long long* __restrict__ bp_packed)
{
    int jg = blockIdx.x >> 6;        // 0..3 (j-group)
    int b  = blockIdx.x & 63;        // same-b blocks adjacent -> same XCD L2
    int tid = threadIdx.x;
    __shared__ unsigned long long s1[8 * 512];  // 32 KB
    __shared__ unsigned long long s2[64];

    float4 T[8]; float TA[8];
    #pragma unroll
    for (int jj = 0; jj < 8; jj++) {
        T[jj] = ((const float4*)truths)[b * NOBJ + jg * 8 + jj];
        TA[jj] = (T[jj].z - T[jj].x) * (T[jj].w - T[jj].y);
    }
    unsigned long long key[8];
    #pragma unroll
    for (int jj = 0; jj < 8; jj++) key[jj] = 0x407FFFFFFFFFFFFFULL;  // pack(-1.0, p=0)

    for (int i = tid; i < P; i += 1024) {
        size_t bpi = (size_t)b * P + i;
        float2 cc = ((const float2*)arm_conf)[bpi];
        bool resv = (cc.x - cc.y) < LN99;
        float4 l = ((const float4*)arm_loc)[bpi];
        float4 pr = ((const float4*)priors)[i];
        float dcx = pr.x + l.x * 0.1f * pr.z;
        float dcy = pr.y + l.y * 0.1f * pr.w;
        float dw = pr.z * __expf(l.z * 0.2f);
        float dh = pr.w * __expf(l.w * 0.2f);
        float x1 = dcx - dw * 0.5f;
        float y1 = dcy - dh * 0.5f;
        float x2 = dcx + dw * 0.5f;
        float y2 = dcy + dh * 0.5f;
        float areaP = (x2 - x1) * (y2 - y1);
        #pragma unroll
        for (int jj = 0; jj < 8; jj++) {
            float iw = fmaxf(fminf(x2, T[jj].z) - fmaxf(x1, T[jj].x), 0.f);
            float ih = fmaxf(fminf(y2, T[jj].w) - fmaxf(y1, T[jj].y), 0.f);
            float inter = iw * ih;
            float iou = inter * __builtin_amdgcn_rcpf(TA[jj] + areaP - inter);
            // iou >= 0 -> monotone key = bits | signbit
            unsigned long long k =
                ((unsigned long long)(__float_as_uint(iou) | 0x80000000u) << 32)
                | (unsigned)~(unsigned)i;
            if (resv && k > key[jj]) key[jj] = k;
        }
    }

    // pair pre-reduce (1 shuffle step), even lanes write [8][512]
    #pragma unroll
    for (int jj = 0; jj < 8; jj++) {
        unsigned long long o = __shfl_xor(key[jj], 1, 64);
        if (o > key[jj]) key[jj] = o;
    }
    if ((tid & 1) == 0) {
        #pragma unroll
        for (int jj = 0; jj < 8; jj++) s1[jj * 512 + (tid >> 1)] = key[jj];
    }
    __syncthreads();

    // stage A: 512 -> 128 per j (128 threads/j, 4 reads each, rotated for banks)
    unsigned long long m1 = 0;
    {
        int j = tid >> 7, c = tid & 127;
        #pragma unroll
        for (int i = 0; i < 4; i++) {
            unsigned long long v = s1[j * 512 + c * 4 + ((i + c) & 3)];
            if (v > m1) m1 = v;
        }
    }
    __syncthreads();
    s1[tid] = m1;  // re-use as [8][128]
    __syncthreads();

    // stage B: 128 -> 8 per j
    if (tid < 64) {
        int j = tid >> 3, c = tid & 7;
        unsigned long long m2 = 0;
        #pragma unroll
        for (int i = 0; i < 16; i++) {
            unsigned long long v = s1[j * 128 + c * 16 + ((i + c) & 15)];
            if (v > m2) m2 = v;
        }
        s2[tid] = m2;
    }
    __syncthreads();

    // stage C: 8 -> 1, write result (no atomics, no extra init kernel)
    if (tid < 8) {
        unsigned long long m3 = 0;
        #pragma unroll
        for (int i = 0; i < 8; i++) {
            unsigned long long v = s2[tid * 8 + ((i + tid) & 7)];
            if (v > m3) m3 = v;
        }
        bp_packed[b * NOBJ + jg * 8 + tid] = m3;
    }
}

// ---------------- p2: per-prior match + override + CE + smooth-L1 + mine -----
__global__ __launch_bounds__(256) void k_p2(
    const float* __restrict__ arm_loc, const float* __restrict__ arm_conf,
    const float* __restrict__ odm_loc, const float* __restrict__ odm_conf,
    const float* __restrict__ priors, const float* __restrict__ truths,
    const int* __restrict__ labels,
    const unsigned long long* __restrict__ bp_packed,
    float* __restrict__ mine, int* __restrict__ num_pos,
    float* __restrict__ ll_b, float* __restrict__ lc_b)
{
    int b = blockIdx.y;
    int pbase = blockIdx.x * 256;
    int tid = threadIdx.x;
    int p = pbase + tid;

    __shared__ float soc[256 * NC];   // 21.5 KB staged odm_conf (coalesced)
    __shared__ float4 s_tr[NOBJ];
    __shared__ float s_ta[NOBJ];
    __shared__ unsigned s_pi[NOBJ];
    __shared__ int s_lab[NOBJ];

    if (tid < NOBJ) {
        float4 t = ((const float4*)truths)[b * NOBJ + tid];
        s_tr[tid] = t;
        s_ta[tid] = (t.z - t.x) * (t.w - t.y);
        s_pi[tid] = ~(unsigned)(bp_packed[b * NOBJ + tid] & 0xFFFFFFFFULL);
        s_lab[tid] = labels[b * NOBJ + tid];
    }
    // coalesced odm_conf stage: contiguous [prior][class] floats
    {
        int nval = P - pbase; if (nval > 256) nval = 256;
        int tot = nval * NC;
        const float* ocb = odm_conf + ((size_t)b * P + pbase) * NC;
        for (int i = tid; i < tot; i += 256) soc[i] = ocb[i];
    }
    __syncthreads();

    float ll = 0.f, lc = 0.f; int np = 0;
    if (p < P) {
        size_t bpi = (size_t)b * P + p;
        float2 cc = ((const float2*)arm_conf)[bpi];
        bool resv = (cc.x - cc.y) < LN99;

        int bi = 0; bool ge = false;
        float rx1 = 0.f, ry1 = 0.f, rx2 = 0.f, ry2 = 0.f;
        if (resv) {
            float4 l = ((const float4*)arm_loc)[bpi];
            float4 pr = ((const float4*)priors)[p];
            float dcx = pr.x + l.x * 0.1f * pr.z;
            float dcy = pr.y + l.y * 0.1f * pr.w;
            float dw = pr.z * __expf(l.z * 0.2f);
            float dh = pr.w * __expf(l.w * 0.2f);
            rx1 = dcx - dw * 0.5f; ry1 = dcy - dh * 0.5f;
            rx2 = dcx + dw * 0.5f; ry2 = dcy + dh * 0.5f;
            float areaP = (rx2 - rx1) * (ry2 - ry1);
            float bestv = -1.f;
            #pragma unroll
            for (int j = 0; j < NOBJ; j++) {
                float4 t = s_tr[j];
                float iw = fmaxf(fminf(rx2, t.z) - fmaxf(rx1, t.x), 0.f);
                float ih = fmaxf(fminf(ry2, t.w) - fmaxf(ry1, t.y), 0.f);
                float inter = iw * ih;
                float iou = inter * __builtin_amdgcn_rcpf(s_ta[j] + areaP - inter);
                if (iou > bestv) { bestv = iou; bi = j; }  // first-max tie-break
            }
            ge = !(bestv < 0.5f);
        }
        // force-match override; ascending j = last-write-wins (matches JAX scatter)
        #pragma unroll
        for (int j = 0; j < NOBJ; j++)
            if (s_pi[j] == (unsigned)p) { ge = true; bi = j; }

        int conf = !resv ? -1 : (ge ? s_lab[bi] + 1 : 0);

        // CE from staged odm_conf (stride-21 LDS reads: odd stride, cheap)
        const float* row = &soc[tid * NC];
        float m = row[0];
        #pragma unroll
        for (int k = 1; k < NC; k++) m = fmaxf(m, row[k]);
        float s = 0.f;
        #pragma unroll
        for (int k = 0; k < NC; k++) s += __expf(row[k] - m);
        int t0 = conf > 0 ? conf : 0;
        float ce = m + __logf(s) - row[t0];

        bool pos = conf > 0;
        mine[bpi] = (pos || conf == -1) ? 0.f : ce;

        if (pos) {
            np = 1; lc = ce;
            float rcx = (rx1 + rx2) * 0.5f, rcy = (ry1 + ry2) * 0.5f;
            float rw = rx2 - rx1, rh = ry2 - ry1;
            float4 tb = s_tr[bi];
            float g0 = ((tb.x + tb.z) * 0.5f - rcx) * __builtin_amdgcn_rcpf(0.1f * rw);
            float g1 = ((tb.y + tb.w) * 0.5f - rcy) * __builtin_amdgcn_rcpf(0.1f * rh);
            float g2 = __logf((tb.z - tb.x) * __builtin_amdgcn_rcpf(rw)) * 5.0f;
            float g3 = __logf((tb.w - tb.y) * __builtin_amdgcn_rcpf(rh)) * 5.0f;
            float4 ol = ((const float4*)odm_loc)[bpi];
            float gt[4] = {g0, g1, g2, g3};
            float od[4] = {ol.x, ol.y, ol.z, ol.w};
            #pragma unroll
            for (int k = 0; k < 4; k++) {
                float d = fabsf(od[k] - gt[k]);
                ll += (d < 1.f) ? 0.5f * d * d : d - 0.5f;
            }
        }
    }

    #pragma unroll
    for (int off = 32; off; off >>= 1) {
        ll += __shfl_xor(ll, off, 64);
        lc += __shfl_xor(lc, off, 64);
        np += __shfl_xor(np, off, 64);
    }
    __shared__ float sll[4], slc[4];
    __shared__ int snp[4];
    int wid = tid >> 6, lane = tid & 63;
    if (lane == 0) { sll[wid] = ll; slc[wid] = lc; snp[wid] = np; }
    __syncthreads();
    if (tid == 0) {
        float a = 0.f, c = 0.f; int n = 0;
        for (int w = 0; w < 4; w++) { a += sll[w]; c += slc[w]; n += snp[w]; }
        if (a != 0.f) atomicAdd(&ll_b[b], a);
        if (c != 0.f) atomicAdd(&lc_b[b], c);
        if (n) atomicAdd(&num_pos[b], n);
    }
}

// ---------------- per-batch top-K CE sum via 8-bit radix select --------------
__global__ __launch_bounds__(256) void k_select(
    const float* __restrict__ mine, const int* __restrict__ num_pos,
    float* __restrict__ lc_b)
{
    int b = blockIdx.x;
    int tid = threadIdx.x;
    int K0 = num_pos[b] * 3;
    if (K0 > P - 1) K0 = P - 1;
    if (K0 <= 0) return;
    const float* row = mine + (size_t)b * P;

    __shared__ unsigned hist[256];
    __shared__ unsigned s_beta, s_K;

    unsigned K = (unsigned)K0;
    unsigned prefix = 0, maskDone = 0;

    for (int pass = 0; pass < 4; pass++) {
        int shift = 24 - pass * 8;
        hist[tid] = 0;
        __syncthreads();
        for (int i = tid; i < P; i += 256) {
            unsigned bits = __float_as_uint(row[i]);
            if ((bits & maskDone) == prefix) atomicAdd(&hist[(bits >> shift) & 255u], 1u);
        }
        __syncthreads();
        if (tid < 64) {  // single-wave suffix scan: 4 bins/lane + shfl_down
            unsigned u0 = hist[tid * 4 + 0], u1 = hist[tid * 4 + 1];
            unsigned u2 = hist[tid * 4 + 2], u3 = hist[tid * 4 + 3];
            unsigned sum4 = u0 + u1 + u2 + u3;
            unsigned x = sum4;
            #pragma unroll
            for (int off = 1; off < 64; off <<= 1) {
                unsigned y = __shfl_down(x, off, 64);
                if (tid + off < 64) x += y;
            }
            // x = suffix sum starting at bin tid*4
            unsigned sf0 = x, sf1 = x - u0, sf2 = x - u0 - u1, sf3 = x - u0 - u1 - u2;
            unsigned sf4 = x - sum4;
            if (sf0 >= K && sf1 < K) { s_beta = tid * 4 + 0; s_K = K - sf1; }
            if (sf1 >= K && sf2 < K) { s_beta = tid * 4 + 1; s_K = K - sf2; }
            if (sf2 >= K && sf3 < K) { s_beta = tid * 4 + 2; s_K = K - sf3; }
            if (sf3 >= K && sf4 < K) { s_beta = tid * 4 + 3; s_K = K - sf4; }
        }
        __syncthreads();
        prefix |= (s_beta << shift);
        maskDone |= (0xFFu << shift);
        K = s_K;
        __syncthreads();
    }

    unsigned tBits = prefix;
    float t = __uint_as_float(tBits);

    unsigned mcnt = 0; float ssum = 0.f;
    for (int i = tid; i < P; i += 256) {
        float v = row[i];
        if (__float_as_uint(v) > tBits) { mcnt++; ssum += v; }
    }
    #pragma unroll
    for (int off = 32; off; off >>= 1) {
        mcnt += __shfl_xor(mcnt, off, 64);
        ssum += __shfl_xor(ssum, off, 64);
    }
    __shared__ float sS[4];
    __shared__ unsigned sM[4];
    int wid = tid >> 6, lane = tid & 63;
    if (lane == 0) { sS[wid] = ssum; sM[wid] = mcnt; }
    __syncthreads();
    if (tid == 0) {
        float S = 0.f; unsigned M = 0;
        for (int w = 0; w < 4; w++) { S += sS[w]; M += sM[w]; }
        atomicAdd(&lc_b[b], S + (float)(K0 - (int)M) * t);
    }
}

// ---------------- finalize ---------------------------------------------------
__global__ void k_final(const int* __restrict__ num_pos, const float* __restrict__ ll_b,
                        const float* __restrict__ lc_b, float* __restrict__ out) {
    int t = threadIdx.x;  // 64 threads
    int np = num_pos[t];
    float ll = ll_b[t];
    float lc = lc_b[t];
    #pragma unroll
    for (int off = 32; off; off >>= 1) {
        np += __shfl_xor(np, off, 64);
        ll += __shfl_xor(ll, off, 64);
        lc += __shfl_xor(lc, off, 64);
    }
    if (t == 0) {
        float tn = (float)np;
        out[0] = ll / tn;
        out[1] = lc / tn;
    }
}

extern "C" void kernel_launch(void* const* d_in, const int* in_sizes, int n_in,
                              void* d_out, int out_size, void* d_ws, size_t ws_size,
                              hipStream_t stream) {
    const float* arm_loc  = (const float*)d_in[0];
    const float* arm_conf = (const float*)d_in[1];
    const float* odm_loc  = (const float*)d_in[2];
    const float* odm_conf = (const float*)d_in[3];
    const float* priors   = (const float*)d_in[4];
    const float* truths   = (const float*)d_in[5];
    const int*   labels   = (const int*)d_in[6];
    float* out = (float*)d_out;

    char* ws = (char*)d_ws;
    const size_t BPTOT = (size_t)B * P;
    float* mine = (float*)ws;                                        // BPTOT f32
    unsigned long long* bp_packed = (unsigned long long*)(ws + 4ull * BPTOT);
    int*   num_pos = (int*)(ws + 4ull * BPTOT + 8ull * B * NOBJ);
    float* ll_b    = (float*)(ws + 4ull * BPTOT + 8ull * B * NOBJ + 4ull * B);
    float* lc_b    = (float*)(ws + 4ull * BPTOT + 8ull * B * NOBJ + 8ull * B);

    k_init<<<1, 64, 0, stream>>>(num_pos, ll_b, lc_b);
    k_p1b<<<256, 1024, 0, stream>>>(arm_loc, arm_conf, priors, truths, bp_packed);
    k_p2<<<dim3(64, B), 256, 0, stream>>>(arm_loc, arm_conf, odm_loc, odm_conf,
                                          priors, truths, labels, bp_packed,
                                          mine, num_pos, ll_b, lc_b);
    k_select<<<B, 256, 0, stream>>>(mine, num_pos, lc_b);
    k_final<<<1, 64, 0, stream>>>(num_pos, ll_b, lc_b, out);
}

// Round 5
// 248.925 us; speedup vs baseline: 1.1324x; 1.1324x over previous
//
#include <hip/hip_runtime.h>

#define B 64
#define P 16320
#define NOBJ 32
#define NC 21
#define CHUNK 4080   // P/4

__device__ constexpr float LN99 = 4.59511985013459f;  // softmax(c1)>0.01 <=> c0-c1 < ln99
#define SENT 0x407FFFFFFFFFFFFFULL                    // pack(-1.0f, prior 0)

// ---------------- init: zero per-batch accumulators --------------------------
__global__ void k_init(int* num_pos, float* ll_b, float* lc_b) {
    int t = threadIdx.x;
    if (t < B) { num_pos[t] = 0; ll_b[t] = 0.f; lc_b[t] = 0.f; }
}

// ---------------- p1: decode + IoU; per-prior argmax -> bt_pack;
//                  per-truth partial argmax -> bp_part[b*4+c][j] ---------------
// One block per (b, P/4 chunk). Each thread owns 4 priors (boxes in regs),
// loops 32 truths x 4 priors tracking both argmaxes; 2-step pair shuffle +
// shallow LDS tree for the per-truth reduction. Arm data read exactly once.
__global__ __launch_bounds__(1024) void k_p1(
    const float* __restrict__ arm_loc, const float* __restrict__ arm_conf,
    const float* __restrict__ priors, const float* __restrict__ truths,
    int* __restrict__ bt_pack, unsigned long long* __restrict__ bp_part)
{
    int b = blockIdx.x >> 2, c = blockIdx.x & 3;
    int tid = threadIdx.x;
    int base = c * CHUNK;

    __shared__ float4 s_tr[NOBJ];
    __shared__ float s_ta[NOBJ];
    __shared__ unsigned long long s1[NOBJ * 256];  // 64 KB
    __shared__ unsigned long long s2[1024];        // 8 KB

    if (tid < NOBJ) {
        float4 t = ((const float4*)truths)[b * NOBJ + tid];
        s_tr[tid] = t;
        s_ta[tid] = (t.z - t.x) * (t.w - t.y);
    }
    __syncthreads();

    float x1[4], y1[4], x2[4], y2[4], ap[4];
    bool rs[4], av[4];
    #pragma unroll
    for (int g = 0; g < 4; g++) {
        int off = g * 1024 + tid;
        av[g] = off < CHUNK;            // only g==3 partial (tid<1008)
        rs[g] = false;
        x1[g] = y1[g] = x2[g] = y2[g] = ap[g] = 0.f;
        if (av[g]) {
            int p = base + off;
            size_t bpi = (size_t)b * P + p;
            float2 cc = ((const float2*)arm_conf)[bpi];
            rs[g] = (cc.x - cc.y) < LN99;
            float4 l = ((const float4*)arm_loc)[bpi];
            float4 pr = ((const float4*)priors)[p];
            float dcx = pr.x + l.x * 0.1f * pr.z;
            float dcy = pr.y + l.y * 0.1f * pr.w;
            float dw = pr.z * __expf(l.z * 0.2f);
            float dh = pr.w * __expf(l.w * 0.2f);
            x1[g] = dcx - dw * 0.5f; y1[g] = dcy - dh * 0.5f;
            x2[g] = dcx + dw * 0.5f; y2[g] = dcy + dh * 0.5f;
            ap[g] = (x2[g] - x1[g]) * (y2[g] - y1[g]);
        }
    }

    float bv[4] = {-1.f, -1.f, -1.f, -1.f};
    int bj[4] = {0, 0, 0, 0};

    #pragma unroll
    for (int j = 0; j < NOBJ; j++) {
        float4 t = s_tr[j];
        float ta = s_ta[j];
        float jv = -1.f; int jg = 0;
        #pragma unroll
        for (int g = 0; g < 4; g++) {
            float iw = fmaxf(fminf(x2[g], t.z) - fmaxf(x1[g], t.x), 0.f);
            float ih = fmaxf(fminf(y2[g], t.w) - fmaxf(y1[g], t.y), 0.f);
            float inter = iw * ih;
            float iou = inter * __builtin_amdgcn_rcpf(ta + ap[g] - inter);
            float iou_r = av[g] ? iou : -1.f;             // raw iou (av-masked)
            if (iou_r > bv[g]) { bv[g] = iou_r; bj[g] = j; }   // first-j tie-break
            float iou_m = rs[g] ? iou_r : -1.f;           // reserve-masked (ovm)
            if (iou_m > jv) { jv = iou_m; jg = g; }       // first-p tie-break (g asc)
        }
        unsigned long long pk = 0ULL;
        if (jv >= 0.f) {
            unsigned p = (unsigned)(base + jg * 1024 + tid);
            pk = ((unsigned long long)(__float_as_uint(jv) | 0x80000000u) << 32)
               | (unsigned)~p;                            // (val, ~p): ties -> min p
        }
        { unsigned long long o = __shfl_xor(pk, 1, 64); if (o > pk) pk = o; }
        { unsigned long long o = __shfl_xor(pk, 2, 64); if (o > pk) pk = o; }
        if ((tid & 3) == 0) s1[j * 256 + (tid >> 2)] = pk;
    }

    // per-prior result: (bi<<2) | (overlap>=0.5)<<1 | reserve
    #pragma unroll
    for (int g = 0; g < 4; g++) {
        if (av[g]) {
            int p = base + g * 1024 + tid;
            int bt = rs[g] ? ((bj[g] << 2) | ((bv[g] >= 0.5f) ? 2 : 0) | 1) : 0;
            bt_pack[(size_t)b * P + p] = bt;
        }
    }
    __syncthreads();

    // stage2: [32][256] -> [32][32] (strided reads: 2-way bank alias, free)
    {
        int j = tid >> 5, r = tid & 31;
        unsigned long long m = 0;
        #pragma unroll
        for (int q = 0; q < 8; q++) {
            unsigned long long v = s1[j * 256 + q * 32 + r];
            if (v > m) m = v;
        }
        s2[tid] = m;
    }
    __syncthreads();
    // stage3: [32][32] -> 1 per j (rotated reads)
    if (tid < NOBJ) {
        unsigned long long m = 0;
        #pragma unroll
        for (int i = 0; i < 32; i++) {
            unsigned long long v = s2[tid * 32 + ((i + tid) & 31)];
            if (v > m) m = v;
        }
        bp_part[blockIdx.x * NOBJ + tid] = m;   // may be 0 = "no reserve in chunk"
    }
}

// ---------------- p2: conf target + override + CE + smooth-L1 + mine ---------
__global__ __launch_bounds__(256) void k_p2(
    const float* __restrict__ arm_loc, const float* __restrict__ odm_loc,
    const float* __restrict__ odm_conf, const float* __restrict__ priors,
    const float* __restrict__ truths, const int* __restrict__ labels,
    const int* __restrict__ bt_pack, const unsigned long long* __restrict__ bp_part,
    float* __restrict__ mine, int* __restrict__ num_pos,
    float* __restrict__ ll_b, float* __restrict__ lc_b)
{
    int b = blockIdx.y;
    int pbase = blockIdx.x * 256;
    int tid = threadIdx.x;
    int p = pbase + tid;

    __shared__ float soc[256 * NC];   // 21.5 KB
    __shared__ float4 s_tr[NOBJ];
    __shared__ int s_lab[NOBJ];
    __shared__ int s_ov[256];

    s_ov[tid] = -1;
    if (tid < NOBJ) {
        float4 t = ((const float4*)truths)[b * NOBJ + tid];
        s_tr[tid] = t;
        s_lab[tid] = labels[b * NOBJ + tid];
    }
    // coalesced float4 staging of odm_conf (block base is 16B-aligned)
    {
        int nval = P - pbase; if (nval > 256) nval = 256;
        int tot4 = (nval * NC) >> 2;   // divisible: nval in {256,192}
        const float4* src = (const float4*)(odm_conf + ((size_t)b * P + pbase) * NC);
        float4* dst = (float4*)soc;
        for (int i = tid; i < tot4; i += 256) dst[i] = src[i];
    }
    __syncthreads();

    // combine per-chunk partials; build override map (atomicMax j = last-write-wins)
    if (tid < NOBJ) {
        unsigned long long m = SENT;
        #pragma unroll
        for (int c = 0; c < 4; c++) {
            unsigned long long v = bp_part[(b * 4 + c) * NOBJ + tid];
            if (v > m) m = v;
        }
        int pi = (int)~(unsigned)(m & 0xFFFFFFFFULL);
        if (pi >= pbase && pi < pbase + 256) atomicMax(&s_ov[pi - pbase], tid);
    }
    __syncthreads();

    float ll = 0.f, lc = 0.f; int np = 0;
    if (p < P) {
        size_t bpi = (size_t)b * P + p;
        int bt = bt_pack[bpi];
        bool resv = bt & 1;
        int ge = (bt >> 1) & 1;
        int bi = bt >> 2;
        int ov = s_ov[tid];
        if (ov >= 0) { ge = 1; bi = ov; }   // forced match (overlap := 2.0)

        int conf = !resv ? -1 : (ge ? s_lab[bi] + 1 : 0);

        const float* row = &soc[tid * NC];  // stride 21 floats: 2-way alias, free
        float mx = row[0];
        #pragma unroll
        for (int k = 1; k < NC; k++) mx = fmaxf(mx, row[k]);
        float s = 0.f;
        #pragma unroll
        for (int k = 0; k < NC; k++) s += __expf(row[k] - mx);
        int t0 = conf > 0 ? conf : 0;
        float ce = mx + __logf(s) - row[t0];

        mine[bpi] = (conf == 0) ? ce : 0.f;

        if (conf > 0) {
            np = 1; lc = ce;
            float4 l = ((const float4*)arm_loc)[bpi];     // sparse reads (pos only)
            float4 pr = ((const float4*)priors)[p];
            float dcx = pr.x + l.x * 0.1f * pr.z;
            float dcy = pr.y + l.y * 0.1f * pr.w;
            float dw = pr.z * __expf(l.z * 0.2f);
            float dh = pr.w * __expf(l.w * 0.2f);
            float rx1 = dcx - dw * 0.5f, ry1 = dcy - dh * 0.5f;
            float rx2 = dcx + dw * 0.5f, ry2 = dcy + dh * 0.5f;
            float rcx = (rx1 + rx2) * 0.5f, rcy = (ry1 + ry2) * 0.5f;
            float rw = rx2 - rx1, rh = ry2 - ry1;
            float4 tb = s_tr[bi];
            float g0 = ((tb.x + tb.z) * 0.5f - rcx) * __builtin_amdgcn_rcpf(0.1f * rw);
            float g1 = ((tb.y + tb.w) * 0.5f - rcy) * __builtin_amdgcn_rcpf(0.1f * rh);
            float g2 = __logf((tb.z - tb.x) * __builtin_amdgcn_rcpf(rw)) * 5.0f;
            float g3 = __logf((tb.w - tb.y) * __builtin_amdgcn_rcpf(rh)) * 5.0f;
            float4 ol = ((const float4*)odm_loc)[bpi];
            float gt[4] = {g0, g1, g2, g3};
            float od[4] = {ol.x, ol.y, ol.z, ol.w};
            #pragma unroll
            for (int k = 0; k < 4; k++) {
                float d = fabsf(od[k] - gt[k]);
                ll += (d < 1.f) ? 0.5f * d * d : d - 0.5f;
            }
        }
    }

    #pragma unroll
    for (int off = 32; off; off >>= 1) {
        ll += __shfl_xor(ll, off, 64);
        lc += __shfl_xor(lc, off, 64);
        np += __shfl_xor(np, off, 64);
    }
    __shared__ float sll[4], slc[4];
    __shared__ int snp[4];
    int wid = tid >> 6, lane = tid & 63;
    if (lane == 0) { sll[wid] = ll; slc[wid] = lc; snp[wid] = np; }
    __syncthreads();
    if (tid == 0) {
        float a = 0.f, cq = 0.f; int n = 0;
        for (int w = 0; w < 4; w++) { a += sll[w]; cq += slc[w]; n += snp[w]; }
        if (a != 0.f) atomicAdd(&ll_b[b], a);
        if (cq != 0.f) atomicAdd(&lc_b[b], cq);
        if (n) atomicAdd(&num_pos[b], n);
    }
}

// ---------------- per-batch top-K CE sum: LDS-resident radix select ----------
// Row (65 KB) staged once into LDS; per-wave padded histograms kill the
// same-bin atomic serialization (CE exponents concentrate in ~2 bins).
__global__ __launch_bounds__(1024) void k_select(
    const float* __restrict__ mine, const int* __restrict__ num_pos,
    float* __restrict__ lc_b)
{
    int b = blockIdx.x, tid = threadIdx.x;
    int K0 = num_pos[b] * 3;
    if (K0 > P - 1) K0 = P - 1;
    if (K0 <= 0) return;

    __shared__ float4 s_row4[P / 4];        // 65280 B
    __shared__ unsigned hist[16 * 257];     // 16448 B, per-wave + pad
    __shared__ unsigned s_merged[256];
    __shared__ unsigned s_beta, s_K;
    __shared__ float sS[16];
    __shared__ unsigned sM[16];

    const float4* src = (const float4*)(mine + (size_t)b * P);
    for (int i = tid; i < P / 4; i += 1024) s_row4[i] = src[i];

    unsigned K = (unsigned)K0, prefix = 0, maskDone = 0;
    int wid = tid >> 6;

    for (int pass = 0; pass < 4; pass++) {
        int shift = 24 - pass * 8;
        for (int i = tid; i < 16 * 257; i += 1024) hist[i] = 0;
        __syncthreads();
        for (int i = tid; i < P / 4; i += 1024) {
            float4 v = s_row4[i];
            float vv[4] = {v.x, v.y, v.z, v.w};
            #pragma unroll
            for (int e = 0; e < 4; e++) {
                unsigned bits = __float_as_uint(vv[e]);
                if ((bits & maskDone) == prefix)
                    atomicAdd(&hist[wid * 257 + ((bits >> shift) & 255u)], 1u);
            }
        }
        __syncthreads();
        if (tid < 256) {
            unsigned t = 0;
            #pragma unroll
            for (int w = 0; w < 16; w++) t += hist[w * 257 + tid];
            s_merged[tid] = t;
        }
        __syncthreads();
        if (tid < 64) {   // single-wave suffix scan: 4 bins/lane + shfl_down
            unsigned u0 = s_merged[tid * 4 + 0], u1 = s_merged[tid * 4 + 1];
            unsigned u2 = s_merged[tid * 4 + 2], u3 = s_merged[tid * 4 + 3];
            unsigned sum4 = u0 + u1 + u2 + u3;
            unsigned x = sum4;
            #pragma unroll
            for (int off = 1; off < 64; off <<= 1) {
                unsigned y = __shfl_down(x, off, 64);
                if (tid + off < 64) x += y;
            }
            unsigned sf0 = x, sf1 = x - u0, sf2 = x - u0 - u1, sf3 = x - u0 - u1 - u2;
            unsigned sf4 = x - sum4;
            if (sf0 >= K && sf1 < K) { s_beta = tid * 4 + 0; s_K = K - sf1; }
            if (sf1 >= K && sf2 < K) { s_beta = tid * 4 + 1; s_K = K - sf2; }
            if (sf2 >= K && sf3 < K) { s_beta = tid * 4 + 2; s_K = K - sf3; }
            if (sf3 >= K && sf4 < K) { s_beta = tid * 4 + 3; s_K = K - sf4; }
        }
        __syncthreads();
        prefix |= (s_beta << shift);
        maskDone |= (0xFFu << shift);
        K = s_K;
        __syncthreads();
    }

    unsigned tBits = prefix;
    float t = __uint_as_float(tBits);

    unsigned mcnt = 0; float ssum = 0.f;
    for (int i = tid; i < P / 4; i += 1024) {
        float4 v = s_row4[i];
        float vv[4] = {v.x, v.y, v.z, v.w};
        #pragma unroll
        for (int e = 0; e < 4; e++) {
            if (__float_as_uint(vv[e]) > tBits) { mcnt++; ssum += vv[e]; }
        }
    }
    #pragma unroll
    for (int off = 32; off; off >>= 1) {
        mcnt += __shfl_xor(mcnt, off, 64);
        ssum += __shfl_xor(ssum, off, 64);
    }
    int lane = tid & 63;
    if (lane == 0) { sS[wid] = ssum; sM[wid] = mcnt; }
    __syncthreads();
    if (tid == 0) {
        float S = 0.f; unsigned M = 0;
        for (int w = 0; w < 16; w++) { S += sS[w]; M += sM[w]; }
        atomicAdd(&lc_b[b], S + (float)(K0 - (int)M) * t);
    }
}

// ---------------- finalize ---------------------------------------------------
__global__ void k_final(const int* __restrict__ num_pos, const float* __restrict__ ll_b,
                        const float* __restrict__ lc_b, float* __restrict__ out) {
    int t = threadIdx.x;  // 64 threads
    int np = num_pos[t];
    float ll = ll_b[t];
    float lc = lc_b[t];
    #pragma unroll
    for (int off = 32; off; off >>= 1) {
        np += __shfl_xor(np, off, 64);
        ll += __shfl_xor(ll, off, 64);
        lc += __shfl_xor(lc, off, 64);
    }
    if (t == 0) {
        float tn = (float)np;
        out[0] = ll / tn;
        out[1] = lc / tn;
    }
}

extern "C" void kernel_launch(void* const* d_in, const int* in_sizes, int n_in,
                              void* d_out, int out_size, void* d_ws, size_t ws_size,
                              hipStream_t stream) {
    const float* arm_loc  = (const float*)d_in[0];
    const float* arm_conf = (const float*)d_in[1];
    const float* odm_loc  = (const float*)d_in[2];
    const float* odm_conf = (const float*)d_in[3];
    const float* priors   = (const float*)d_in[4];
    const float* truths   = (const float*)d_in[5];
    const int*   labels   = (const int*)d_in[6];
    float* out = (float*)d_out;

    char* ws = (char*)d_ws;
    const size_t BPTOT = (size_t)B * P;
    float* mine    = (float*)ws;                                   // BPTOT f32
    int*   bt_pack = (int*)(ws + 4ull * BPTOT);                    // BPTOT i32
    unsigned long long* bp_part = (unsigned long long*)(ws + 8ull * BPTOT); // 64*4*32 u64
    int*   num_pos = (int*)(ws + 8ull * BPTOT + 65536ull);
    float* ll_b    = (float*)(ws + 8ull * BPTOT + 65536ull + 256ull);
    float* lc_b    = (float*)(ws + 8ull * BPTOT + 65536ull + 512ull);

    k_init<<<1, 64, 0, stream>>>(num_pos, ll_b, lc_b);
    k_p1<<<256, 1024, 0, stream>>>(arm_loc, arm_conf, priors, truths,
                                   bt_pack, bp_part);
    k_p2<<<dim3(64, B), 256, 0, stream>>>(arm_loc, odm_loc, odm_conf, priors,
                                          truths, labels, bt_pack, bp_part,
                                          mine, num_pos, ll_b, lc_b);
    k_select<<<B, 1024, 0, stream>>>(mine, num_pos, lc_b);
    k_final<<<1, 64, 0, stream>>>(num_pos, ll_b, lc_b, out);
}